// Round 6
// baseline (137.299 us; speedup 1.0000x reference)
//
#include <hip/hip_runtime.h>
#include <hip/hip_bf16.h>

#define NN 2048
#define DD 128

typedef unsigned short u16;
typedef unsigned int u32;
typedef __attribute__((ext_vector_type(8))) short bf16x8;
typedef __attribute__((ext_vector_type(4))) float f32x4;

__device__ __forceinline__ u16 f2bf(float f){
  u32 u = __float_as_uint(f);
  u32 r = (u + 0x7fffu + ((u >> 16) & 1u)) >> 16;
  return (u16)r;
}

__device__ __forceinline__ void gload16(const void* g, void* l){
  __builtin_amdgcn_global_load_lds(
      (const __attribute__((address_space(1))) u32*)g,
      (__attribute__((address_space(3))) u32*)l, 16, 0, 0);
}

// ================= fused prep: role-dispatched by block range =================
// bodies identical to the R5-verified standalone kernels, blockIdx remapped.

template<bool SQW, bool WRITE>
__device__ __forceinline__ void rowpass_body(
    int bid, int tid, const float* __restrict__ src, const float* __restrict__ w,
    u16* __restrict__ dst, float* __restrict__ red){
  int wid = tid >> 6, lane = tid & 63;
  int row = bid * 4 + wid;
  const float4* s4 = (const float4*)(src + (size_t)row * NN);
  float acc = 0.f;
  #pragma unroll
  for (int it = 0; it < NN / 256; ++it){
    int c4 = it * 64 + lane;
    float4 v = s4[c4];
    if constexpr (SQW){
      float4 ww = ((const float4*)w)[c4];
      acc += v.x*v.x*ww.x + v.y*v.y*ww.y + v.z*v.z*ww.z + v.w*v.w*ww.w;
    } else {
      acc += v.x + v.y + v.z + v.w;
    }
    if constexpr (WRITE){
      ushort4 o; o.x = f2bf(v.x); o.y = f2bf(v.y); o.z = f2bf(v.z); o.w = f2bf(v.w);
      ((ushort4*)(dst + (size_t)row * NN))[c4] = o;
    }
  }
  #pragma unroll
  for (int off = 32; off; off >>= 1) acc += __shfl_down(acc, off);
  if (lane == 0) red[row] = acc;
}

__device__ __forceinline__ void transpose_body(
    int bx, int by, int t, float (*tile)[65],
    const float* __restrict__ src, u16* __restrict__ dst){
  int r0 = bx * 64, c0 = by * 64;
  #pragma unroll
  for (int it = 0; it < 4; ++it){
    int chunk = it * 256 + t; int r = chunk >> 4, c4 = chunk & 15;
    float4 v = ((const float4*)(src + (size_t)(r0 + r) * NN + c0))[c4];
    tile[r][c4*4+0] = v.x; tile[r][c4*4+1] = v.y;
    tile[r][c4*4+2] = v.z; tile[r][c4*4+3] = v.w;
  }
  __syncthreads();
  #pragma unroll
  for (int it = 0; it < 4; ++it){
    int chunk = it * 256 + t; int j = chunk >> 4, i4 = chunk & 15;
    ushort4 o;
    o.x = f2bf(tile[i4*4+0][j]); o.y = f2bf(tile[i4*4+1][j]);
    o.z = f2bf(tile[i4*4+2][j]); o.w = f2bf(tile[i4*4+3][j]);
    ((ushort4*)(dst + (size_t)(c0 + j) * NN + r0))[i4] = o;
  }
}

__device__ __forceinline__ void colsum_body(
    int bx, int by, int t, const float* __restrict__ src, float* __restrict__ colsum){
  int j = bx * 256 + t;
  int r0 = by * 64;
  float acc = 0.f;
  for (int r = r0; r < r0 + 64; ++r) acc += src[(size_t)r * NN + j];
  atomicAdd(&colsum[j], acc);
}

__device__ __forceinline__ void emb_body(
    int bid, int t, const float* __restrict__ src, u16* __restrict__ dst,
    float* __restrict__ nrm){
  int rloc = t >> 5, lane32 = t & 31;
  int row = bid * 8 + rloc;
  float4 v = ((const float4*)(src + (size_t)row * DD))[lane32];
  float a = v.x*v.x + v.y*v.y + v.z*v.z + v.w*v.w;
  ushort4 o; o.x = f2bf(v.x); o.y = f2bf(v.y); o.z = f2bf(v.z); o.w = f2bf(v.w);
  ((ushort4*)(dst + (size_t)row * DD))[lane32] = o;
  #pragma unroll
  for (int off = 16; off; off >>= 1) a += __shfl_down(a, off, 32);
  if (lane32 == 0) nrm[row] = a;
}

// role ranges: [0,512) rpA | [512,1024) rpT | [1024,1536) rpB |
// [1536,2560) trT | [2560,3584) trB | [3584,3840) colsum |
// [3840,4096) embA | [4096,4352) embB
__global__ __launch_bounds__(256) void k_prep(
    const float* __restrict__ graph,  const float* __restrict__ prob,
    const float* __restrict__ tran,   const float* __restrict__ graphb,
    const float* __restrict__ probb,  const float* __restrict__ emb,
    const float* __restrict__ embb,
    u16* Cs, u16* Tm, u16* Tt, u16* CtT, u16* es, u16* et,
    float* f1, float* f2, float* rs, float* cls, float* ss, float* st)
{
  __shared__ float tile[64][65];
  int b = blockIdx.x, t = threadIdx.x;
  if (b < 512){
    rowpass_body<true, true >(b, t, graph, prob, Cs, f1);
  } else if (b < 1024){
    rowpass_body<false, true >(b - 512, t, tran, nullptr, Tm, rs);
  } else if (b < 1536){
    rowpass_body<true, false>(b - 1024, t, graphb, probb, nullptr, f2);
  } else if (b < 2560){
    int b2 = b - 1536; transpose_body(b2 & 31, b2 >> 5, t, tile, tran, Tt);
  } else if (b < 3584){
    int b2 = b - 2560; transpose_body(b2 & 31, b2 >> 5, t, tile, graphb, CtT);
  } else if (b < 3840){
    int b2 = b - 3584; colsum_body(b2 & 7, b2 >> 3, t, tran, cls);
  } else if (b < 4096){
    emb_body(b - 3840, t, emb, es, ss);
  } else {
    emb_body(b - 4096, t, embb, et, et ? st : st);
  }
}

// ================= main dual-GEMM: sum( (Cs@T) .* (T@Ct) ) =================
// 128x64 dual tile, grid 512 (2 blocks/CU). waves 0-3: U = Cs@T, waves 4-7: V = T@Ct.
// LDS per buf: A1 8KB @0, A2 8KB @8192, B1 4KB @16384, B2 4KB @20480 (bytes).
__global__ __launch_bounds__(512, 4) void k_gw(
    const u16* __restrict__ Cs, const u16* __restrict__ Tt,
    const u16* __restrict__ Tm, const u16* __restrict__ CtT,
    float* __restrict__ accs)
{
  __shared__ u16 lds[2][12288];   // 2 x 24KB
  const int tid = threadIdx.x;
  const int bid = blockIdx.x;
  const int swz = (bid & 7) * 64 + (bid >> 3);   // XCD swizzle (512 % 8 == 0)
  const int bi = swz >> 5;        // 0..15  (128-row panel)
  const int bk = swz & 31;        // 0..31  (64-col panel)
  const int biRow = bi * 128, bkRow = bk * 64;

  const int w = tid >> 6, lane = tid & 63;
  const int l15 = lane & 15, g = lane >> 4;
  const int gsel = w >> 2, wg = w & 3, wr = wg >> 1, wc = wg & 1;

  // A-staging geometry (8KB tile): thread tid stages linear byte [tid*16,+16).
  const int a_line = tid >> 3;                      // 0..63 (128B lines)
  const int a_s = (tid & 7) ^ (a_line & 7);
  const int a_r = a_line * 2 + (a_s >> 2);          // 0..127
  const int a_c8 = a_s & 3;
  // B-staging geometry (4KB tile): thread (tid&255) stages byte [(tid&255)*16,+16).
  const int t2 = tid & 255;
  const int b_line = t2 >> 3;                       // 0..31
  const int b_s = (t2 & 7) ^ (b_line & 7);
  const int b_r = b_line * 2 + (b_s >> 2);          // 0..63
  const int b_c8 = b_s & 3;

  f32x4 acc[4][2];
  #pragma unroll
  for (int m = 0; m < 4; ++m)
    #pragma unroll
    for (int n = 0; n < 2; ++n)
      acc[m][n] = (f32x4){0.f, 0.f, 0.f, 0.f};

  int offA[4], offB[2];
  #pragma unroll
  for (int m = 0; m < 4; ++m){
    int row = wr * 64 + m * 16 + l15;
    int line = row >> 1;
    offA[m] = line * 128 + (((((row & 1) << 2) | g)) ^ (line & 7)) * 16;
  }
  #pragma unroll
  for (int n = 0; n < 2; ++n){
    int rowb = wc * 32 + n * 16 + l15;              // 0..63
    int lineb = rowb >> 1;
    offB[n] = lineb * 128 + (((((rowb & 1) << 2) | g)) ^ (lineb & 7)) * 16;
  }

  auto stage = [&](int buf, int kt){
    const size_t col = (size_t)kt * 32;
    gload16(Cs + (size_t)(biRow + a_r) * NN + col + a_c8 * 8, &lds[buf][0    + w * 512]);
    gload16(Tm + (size_t)(biRow + a_r) * NN + col + a_c8 * 8, &lds[buf][4096 + w * 512]);
    if (w < 4)
      gload16(Tt  + (size_t)(bkRow + b_r) * NN + col + b_c8 * 8, &lds[buf][8192  + w * 512]);
    else
      gload16(CtT + (size_t)(bkRow + b_r) * NN + col + b_c8 * 8, &lds[buf][10240 + (w - 4) * 512]);
  };

  stage(0, 0);
  __syncthreads();

  const int NT = NN / 32;
  for (int kt = 0; kt < NT; ++kt){
    int cur = kt & 1;
    if (kt + 1 < NT) stage(cur ^ 1, kt + 1);
    const char* tA = (const char*)&lds[cur][gsel ? 4096 : 0];
    const char* tB = (const char*)&lds[cur][gsel ? 10240 : 8192];
    bf16x8 av[4], bv[2];
    #pragma unroll
    for (int m = 0; m < 4; ++m) av[m] = *(const bf16x8*)(tA + offA[m]);
    #pragma unroll
    for (int n = 0; n < 2; ++n) bv[n] = *(const bf16x8*)(tB + offB[n]);
    #pragma unroll
    for (int m = 0; m < 4; ++m)
      #pragma unroll
      for (int n = 0; n < 2; ++n)
        acc[m][n] = __builtin_amdgcn_mfma_f32_16x16x32_bf16(av[m], bv[n], acc[m][n], 0, 0, 0);
    __syncthreads();
  }

  // epilogue: U-waves stash 128x64 f32 (32KB) to LDS, V-waves dot with it.
  float* ustash = (float*)&lds[0][0];
  if (gsel == 0){
    #pragma unroll
    for (int m = 0; m < 4; ++m)
      #pragma unroll
      for (int n = 0; n < 2; ++n)
        #pragma unroll
        for (int r = 0; r < 4; ++r){
          int row = wr * 64 + m * 16 + g * 4 + r;   // C/D: row=(lane>>4)*4+reg
          int col = wc * 32 + n * 16 + l15;         //      col=lane&15
          ustash[row * 64 + col] = acc[m][n][r];
        }
  }
  __syncthreads();
  if (gsel == 1){
    float part = 0.f;
    #pragma unroll
    for (int m = 0; m < 4; ++m)
      #pragma unroll
      for (int n = 0; n < 2; ++n)
        #pragma unroll
        for (int r = 0; r < 4; ++r){
          int row = wr * 64 + m * 16 + g * 4 + r;
          int col = wc * 32 + n * 16 + l15;
          part += acc[m][n][r] * ustash[row * 64 + col];
        }
    #pragma unroll
    for (int off = 32; off; off >>= 1) part += __shfl_down(part, off);
    if (lane == 0) atomicAdd(&accs[0], part);
  }
}

// ---------------- term4: sum( T .* (es @ et^T) ) ----------------
__global__ __launch_bounds__(256, 2) void k_embdot(
    const u16* __restrict__ es, const u16* __restrict__ et,
    const float* __restrict__ tran, float* __restrict__ accs)
{
  __shared__ u16 lds[2][16384];   // es tile 32KB, et tile 32KB ([128][128] bf16)
  const int tid = threadIdx.x;
  const int bid = blockIdx.x;
  const int swz = (bid & 7) * 32 + (bid >> 3);
  const int bi = swz >> 4, bj = swz & 15;
  const int w = tid >> 6, lane = tid & 63;
  const int l15 = lane & 15, g = lane >> 4;
  const int wr = w >> 1, wc = w & 1;

  const u16* srcs[2] = {es, et};
  const int panels[2] = {bi * 128, bj * 128};

  #pragma unroll
  for (int tt = 0; tt < 2; ++tt){
    #pragma unroll
    for (int it = 0; it < 8; ++it){
      int chunk = w * 8 + it;            // 0..31, 1KB each
      int r = chunk * 4 + g;             // 0..127
      int s = l15 ^ (r & 15);
      gload16(srcs[tt] + (size_t)(panels[tt] + r) * DD + s * 8,
              &lds[tt][chunk * 512]);
    }
  }
  __syncthreads();

  f32x4 acc[4][4];
  #pragma unroll
  for (int m = 0; m < 4; ++m)
    #pragma unroll
    for (int n = 0; n < 4; ++n)
      acc[m][n] = (f32x4){0.f, 0.f, 0.f, 0.f};

  #pragma unroll
  for (int ks = 0; ks < 4; ++ks){
    bf16x8 av[4], bv[4];
    #pragma unroll
    for (int m = 0; m < 4; ++m){
      int row = wr * 64 + m * 16 + l15;
      int sp = (ks * 4 + g) ^ (row & 15);
      av[m] = *(const bf16x8*)((const char*)&lds[0][0] + row * 256 + sp * 16);
    }
    #pragma unroll
    for (int n = 0; n < 4; ++n){
      int rowb = wc * 64 + n * 16 + l15;
      int spb = (ks * 4 + g) ^ (rowb & 15);
      bv[n] = *(const bf16x8*)((const char*)&lds[1][0] + rowb * 256 + spb * 16);
    }
    #pragma unroll
    for (int m = 0; m < 4; ++m)
      #pragma unroll
      for (int n = 0; n < 4; ++n)
        acc[m][n] = __builtin_amdgcn_mfma_f32_16x16x32_bf16(av[m], bv[n], acc[m][n], 0, 0, 0);
  }

  float part = 0.f;
  #pragma unroll
  for (int m = 0; m < 4; ++m)
    #pragma unroll
    for (int n = 0; n < 4; ++n)
      #pragma unroll
      for (int r = 0; r < 4; ++r){
        int row = bi * 128 + wr * 64 + m * 16 + g * 4 + r;
        int col = bj * 128 + wc * 64 + n * 16 + l15;
        part += tran[(size_t)row * NN + col] * acc[m][n][r];
      }
  #pragma unroll
  for (int off = 32; off; off >>= 1) part += __shfl_down(part, off);
  if (lane == 0) atomicAdd(&accs[1], part);
}

// ---------------- final combine ----------------
__global__ void k_final(const float* __restrict__ f1, const float* __restrict__ f2,
                        const float* __restrict__ rowsum, const float* __restrict__ colsum,
                        const float* __restrict__ ss, const float* __restrict__ st,
                        const float* __restrict__ accs, float* out){
  __shared__ float red[256];
  int t = threadIdx.x;
  float part = 0.f;
  for (int i = t; i < NN; i += 256){
    part += (f1[i] + 0.5f * ss[i]) * rowsum[i];
    part += (f2[i] + 0.5f * st[i]) * colsum[i];
  }
  red[t] = part; __syncthreads();
  for (int s = 128; s; s >>= 1){ if (t < s) red[t] += red[t + s]; __syncthreads(); }
  if (t == 0){
    float total = red[0] - 2.0f * accs[0] - accs[1];
    out[0] = total;   // reference output is float32
  }
}

extern "C" void kernel_launch(void* const* d_in, const int* in_sizes, int n_in,
                              void* d_out, int out_size, void* d_ws, size_t ws_size,
                              hipStream_t stream)
{
  const float* graph  = (const float*)d_in[0];
  const float* emb    = (const float*)d_in[1];
  const float* prob   = (const float*)d_in[2];
  const float* graphb = (const float*)d_in[3];
  const float* embb   = (const float*)d_in[4];
  const float* probb  = (const float*)d_in[5];
  const float* tran   = (const float*)d_in[6];
  (void)in_sizes; (void)n_in; (void)out_size; (void)ws_size;

  char* ws = (char*)d_ws;
  u16* Cs   = (u16*)(ws + 0);          // 8MB  Cs bf16
  u16* Tm   = (u16*)(ws + 8388608);    // 8MB  T bf16
  u16* Tt   = (u16*)(ws + 16777216);   // 8MB  T^T bf16
  u16* CtT  = (u16*)(ws + 25165824);   // 8MB  Ct^T bf16
  u16* es   = (u16*)(ws + 33554432);   // 512KB
  u16* et   = (u16*)(ws + 34078720);   // 512KB
  float* f1   = (float*)(ws + 34603008);
  float* f2   = (float*)(ws + 34611200);
  float* rs   = (float*)(ws + 34619392);
  float* cls  = (float*)(ws + 34627584);
  float* ss   = (float*)(ws + 34635776);
  float* st   = (float*)(ws + 34643968);
  float* accs = (float*)(ws + 34652160);

  // zero all small scratch (f1..accs, contiguous 49184 B) — replaces k_init
  hipMemsetAsync(ws + 34603008, 0, 49216, stream);

  k_prep<<<4352, 256, 0, stream>>>(graph, prob, tran, graphb, probb, emb, embb,
                                   Cs, Tm, Tt, CtT, es, et,
                                   f1, f2, rs, cls, ss, st);
  k_gw<<<512, 512, 0, stream>>>(Cs, Tt, Tm, CtT, accs);
  k_embdot<<<256, 256, 0, stream>>>(es, et, tran, accs);
  k_final<<<1, 256, 0, stream>>>(f1, f2, rs, cls, ss, st, accs, (float*)d_out);
}

// Round 7
// 106.978 us; speedup vs baseline: 1.2834x; 1.2834x over previous
//
#include <hip/hip_runtime.h>
#include <hip/hip_bf16.h>

#define NN 2048
#define DD 128

typedef unsigned short u16;
typedef unsigned int u32;
typedef __attribute__((ext_vector_type(8))) short bf16x8;
typedef __attribute__((ext_vector_type(4))) float f32x4;

__device__ __forceinline__ u16 f2bf(float f){
  u32 u = __float_as_uint(f);
  u32 r = (u + 0x7fffu + ((u >> 16) & 1u)) >> 16;
  return (u16)r;
}

__device__ __forceinline__ void gload16(const void* g, void* l){
  __builtin_amdgcn_global_load_lds(
      (const __attribute__((address_space(1))) u32*)g,
      (__attribute__((address_space(3))) u32*)l, 16, 0, 0);
}

// ================= fused prep: role-dispatched by block range =================

// graph pass: bf16 cast -> Cs, f1[row] = sum(v^2 * prob[c])  (direct write)
__device__ __forceinline__ void rowpass_graph_body(
    int bid, int tid, const float* __restrict__ src, const float* __restrict__ w,
    u16* __restrict__ dst, float* __restrict__ red){
  int wid = tid >> 6, lane = tid & 63;
  int row = bid * 4 + wid;
  const float4* s4 = (const float4*)(src + (size_t)row * NN);
  float acc = 0.f;
  #pragma unroll
  for (int it = 0; it < NN / 256; ++it){
    int c4 = it * 64 + lane;
    float4 v = s4[c4];
    float4 ww = ((const float4*)w)[c4];
    acc += v.x*v.x*ww.x + v.y*v.y*ww.y + v.z*v.z*ww.z + v.w*v.w*ww.w;
    ushort4 o; o.x = f2bf(v.x); o.y = f2bf(v.y); o.z = f2bf(v.z); o.w = f2bf(v.w);
    ((ushort4*)(dst + (size_t)row * NN))[c4] = o;
  }
  #pragma unroll
  for (int off = 32; off; off >>= 1) acc += __shfl_down(acc, off);
  if (lane == 0) red[row] = acc;
}

// tran pass (64x64 tile): write Tm (bf16 copy), Tt (bf16 transpose),
// partial row sums -> atomicAdd(rs), partial col sums -> atomicAdd(cls)
__device__ __forceinline__ void tran_pass_body(
    int bx, int by, int t, float (*tile)[65],
    const float* __restrict__ src,
    u16* __restrict__ Tm, u16* __restrict__ Tt,
    float* __restrict__ rs, float* __restrict__ cls)
{
  int r0 = bx * 64, c0 = by * 64;
  #pragma unroll
  for (int it = 0; it < 4; ++it){
    int chunk = it * 256 + t; int r = chunk >> 4, c4 = chunk & 15;
    float4 v = ((const float4*)(src + (size_t)(r0 + r) * NN + c0))[c4];
    tile[r][c4*4+0] = v.x; tile[r][c4*4+1] = v.y;
    tile[r][c4*4+2] = v.z; tile[r][c4*4+3] = v.w;
    ushort4 o; o.x = f2bf(v.x); o.y = f2bf(v.y); o.z = f2bf(v.z); o.w = f2bf(v.w);
    ((ushort4*)(Tm + (size_t)(r0 + r) * NN + c0))[c4] = o;
  }
  __syncthreads();
  #pragma unroll
  for (int it = 0; it < 4; ++it){
    int chunk = it * 256 + t; int j = chunk >> 4, i4 = chunk & 15;
    ushort4 o;
    o.x = f2bf(tile[i4*4+0][j]); o.y = f2bf(tile[i4*4+1][j]);
    o.z = f2bf(tile[i4*4+2][j]); o.w = f2bf(tile[i4*4+3][j]);
    ((ushort4*)(Tt + (size_t)(c0 + j) * NN + r0))[i4] = o;
  }
  if (t < 64){
    float s = 0.f;
    #pragma unroll
    for (int c = 0; c < 64; ++c) s += tile[t][c];
    atomicAdd(&rs[r0 + t], s);
  } else if (t < 128){
    int c = t - 64; float s = 0.f;
    #pragma unroll
    for (int r = 0; r < 64; ++r) s += tile[r][c];
    atomicAdd(&cls[c0 + c], s);
  }
}

// graphb pass (64x64 tile): write CtT (bf16 transpose),
// f2 partials: f2[j] += sum_i probb[i]*graphb[j,i]^2
__device__ __forceinline__ void graphb_pass_body(
    int bx, int by, int t, float (*tile)[65], float* pb,
    const float* __restrict__ src, const float* __restrict__ probb,
    u16* __restrict__ CtT, float* __restrict__ f2)
{
  int r0 = bx * 64, c0 = by * 64;
  if (t < 64) pb[t] = probb[c0 + t];
  #pragma unroll
  for (int it = 0; it < 4; ++it){
    int chunk = it * 256 + t; int r = chunk >> 4, c4 = chunk & 15;
    float4 v = ((const float4*)(src + (size_t)(r0 + r) * NN + c0))[c4];
    tile[r][c4*4+0] = v.x; tile[r][c4*4+1] = v.y;
    tile[r][c4*4+2] = v.z; tile[r][c4*4+3] = v.w;
  }
  __syncthreads();
  #pragma unroll
  for (int it = 0; it < 4; ++it){
    int chunk = it * 256 + t; int j = chunk >> 4, i4 = chunk & 15;
    ushort4 o;
    o.x = f2bf(tile[i4*4+0][j]); o.y = f2bf(tile[i4*4+1][j]);
    o.z = f2bf(tile[i4*4+2][j]); o.w = f2bf(tile[i4*4+3][j]);
    ((ushort4*)(CtT + (size_t)(c0 + j) * NN + r0))[i4] = o;
  }
  if (t < 64){
    float s = 0.f;
    #pragma unroll
    for (int c = 0; c < 64; ++c){ float v = tile[t][c]; s += v * v * pb[c]; }
    atomicAdd(&f2[r0 + t], s);
  }
}

__device__ __forceinline__ void emb_body(
    int bid, int t, const float* __restrict__ src, u16* __restrict__ dst,
    float* __restrict__ nrm){
  int rloc = t >> 5, lane32 = t & 31;
  int row = bid * 8 + rloc;
  float4 v = ((const float4*)(src + (size_t)row * DD))[lane32];
  float a = v.x*v.x + v.y*v.y + v.z*v.z + v.w*v.w;
  ushort4 o; o.x = f2bf(v.x); o.y = f2bf(v.y); o.z = f2bf(v.z); o.w = f2bf(v.w);
  ((ushort4*)(dst + (size_t)row * DD))[lane32] = o;
  #pragma unroll
  for (int off = 16; off; off >>= 1) a += __shfl_down(a, off, 32);
  if (lane32 == 0) nrm[row] = a;
}

// roles: [0,512) graph | [512,1536) tran | [1536,2560) graphb |
//        [2560,2816) embA | [2816,3072) embB
__global__ __launch_bounds__(256) void k_prep(
    const float* __restrict__ graph,  const float* __restrict__ prob,
    const float* __restrict__ tran,   const float* __restrict__ graphb,
    const float* __restrict__ probb,  const float* __restrict__ emb,
    const float* __restrict__ embb,
    u16* Cs, u16* Tm, u16* Tt, u16* CtT, u16* es, u16* et,
    float* f1, float* f2, float* rs, float* cls, float* ss, float* st)
{
  __shared__ float tile[64][65];
  __shared__ float pb[64];
  int b = blockIdx.x, t = threadIdx.x;
  if (b < 512){
    rowpass_graph_body(b, t, graph, prob, Cs, f1);
  } else if (b < 1536){
    int b2 = b - 512;  tran_pass_body(b2 & 31, b2 >> 5, t, tile, tran, Tm, Tt, rs, cls);
  } else if (b < 2560){
    int b2 = b - 1536; graphb_pass_body(b2 & 31, b2 >> 5, t, tile, pb, graphb, probb, CtT, f2);
  } else if (b < 2816){
    emb_body(b - 2560, t, emb, es, ss);
  } else {
    emb_body(b - 2816, t, embb, et, st);
  }
}

// ================= main dual-GEMM: sum( (Cs@T) .* (T@Ct) ) =================
// R5-verified version: 128x128 dual tile, grid 256.
// waves 0-3: U = Cs @ T (A1=Cs, B1^T=Tt); waves 4-7: V = T @ Ct (A2=T, B2^T=CtT)
__global__ __launch_bounds__(512, 2) void k_gw(
    const u16* __restrict__ Cs, const u16* __restrict__ Tt,
    const u16* __restrict__ Tm, const u16* __restrict__ CtT,
    float* __restrict__ accs)
{
  __shared__ u16 lds[2][4][4096];   // 2 buf x {A1,B1,A2,B2} x 8KB
  const int tid = threadIdx.x;
  const int bid = blockIdx.x;
  const int swz = (bid & 7) * 32 + (bid >> 3);   // XCD swizzle (256 % 8 == 0)
  const int bi = swz >> 4, bk = swz & 15;

  const u16* srcs[4] = {Cs, Tt, Tm, CtT};
  const int panels[4] = {bi * 128, bk * 128, bi * 128, bk * 128};

  const int w = tid >> 6, lane = tid & 63;
  const int l15 = lane & 15, g = lane >> 4;
  const int gsel = w >> 2, wg = w & 3, wr = wg >> 1, wc = wg & 1;

  const int s_line = w * 8 + (lane >> 3);
  const int s_s = (lane & 7) ^ (s_line & 7);
  const int s_r = s_line * 2 + (s_s >> 2);
  const int s_c8 = s_s & 3;

  f32x4 acc[4][4];
  #pragma unroll
  for (int m = 0; m < 4; ++m)
    #pragma unroll
    for (int n = 0; n < 4; ++n)
      acc[m][n] = (f32x4){0.f, 0.f, 0.f, 0.f};

  int offA[4], offB[4];
  #pragma unroll
  for (int m = 0; m < 4; ++m){
    int row = wr * 64 + m * 16 + l15;
    int line = row >> 1;
    offA[m] = line * 128 + (((((row & 1) << 2) | g)) ^ (line & 7)) * 16;
    int rowb = wc * 64 + m * 16 + l15;
    int lineb = rowb >> 1;
    offB[m] = lineb * 128 + (((((rowb & 1) << 2) | g)) ^ (lineb & 7)) * 16;
  }

  auto stage = [&](int buf, int kt){
    const size_t coloff = (size_t)kt * 32 + s_c8 * 8;
    #pragma unroll
    for (int tt = 0; tt < 4; ++tt){
      gload16(srcs[tt] + (size_t)(panels[tt] + s_r) * NN + coloff,
              &lds[buf][tt][w * 512]);
    }
  };

  stage(0, 0);
  __syncthreads();

  const int NT = NN / 32;
  for (int kt = 0; kt < NT; ++kt){
    int cur = kt & 1;
    if (kt + 1 < NT) stage(cur ^ 1, kt + 1);
    const char* tA = (const char*)&lds[cur][gsel * 2][0];
    const char* tB = (const char*)&lds[cur][gsel * 2 + 1][0];
    bf16x8 av[4], bv[4];
    #pragma unroll
    for (int m = 0; m < 4; ++m) av[m] = *(const bf16x8*)(tA + offA[m]);
    #pragma unroll
    for (int n = 0; n < 4; ++n) bv[n] = *(const bf16x8*)(tB + offB[n]);
    #pragma unroll
    for (int m = 0; m < 4; ++m)
      #pragma unroll
      for (int n = 0; n < 4; ++n)
        acc[m][n] = __builtin_amdgcn_mfma_f32_16x16x32_bf16(av[m], bv[n], acc[m][n], 0, 0, 0);
    __syncthreads();
  }

  // epilogue: U-waves stash to LDS (f32 128x128), V-waves dot with it.
  float* ustash = (float*)&lds[0][0][0];
  if (gsel == 0){
    #pragma unroll
    for (int m = 0; m < 4; ++m)
      #pragma unroll
      for (int n = 0; n < 4; ++n)
        #pragma unroll
        for (int r = 0; r < 4; ++r){
          int row = wr * 64 + m * 16 + g * 4 + r;   // C/D: row=(lane>>4)*4+reg
          int col = wc * 64 + n * 16 + l15;         //      col=lane&15
          ustash[row * 128 + col] = acc[m][n][r];
        }
  }
  __syncthreads();
  if (gsel == 1){
    float part = 0.f;
    #pragma unroll
    for (int m = 0; m < 4; ++m)
      #pragma unroll
      for (int n = 0; n < 4; ++n)
        #pragma unroll
        for (int r = 0; r < 4; ++r){
          int row = wr * 64 + m * 16 + g * 4 + r;
          int col = wc * 64 + n * 16 + l15;
          part += acc[m][n][r] * ustash[row * 128 + col];
        }
    #pragma unroll
    for (int off = 32; off; off >>= 1) part += __shfl_down(part, off);
    if (lane == 0) atomicAdd(&accs[0], part);
  }
}

// ---------------- term4: sum( T .* (es @ et^T) ) ----------------
__global__ __launch_bounds__(256, 2) void k_embdot(
    const u16* __restrict__ es, const u16* __restrict__ et,
    const float* __restrict__ tran, float* __restrict__ accs)
{
  __shared__ u16 lds[2][16384];   // es tile 32KB, et tile 32KB ([128][128] bf16)
  const int tid = threadIdx.x;
  const int bid = blockIdx.x;
  const int swz = (bid & 7) * 32 + (bid >> 3);
  const int bi = swz >> 4, bj = swz & 15;
  const int w = tid >> 6, lane = tid & 63;
  const int l15 = lane & 15, g = lane >> 4;
  const int wr = w >> 1, wc = w & 1;

  const u16* srcs[2] = {es, et};
  const int panels[2] = {bi * 128, bj * 128};

  #pragma unroll
  for (int tt = 0; tt < 2; ++tt){
    #pragma unroll
    for (int it = 0; it < 8; ++it){
      int chunk = w * 8 + it;            // 0..31, 1KB each
      int r = chunk * 4 + g;             // 0..127
      int s = l15 ^ (r & 15);
      gload16(srcs[tt] + (size_t)(panels[tt] + r) * DD + s * 8,
              &lds[tt][chunk * 512]);
    }
  }
  __syncthreads();

  f32x4 acc[4][4];
  #pragma unroll
  for (int m = 0; m < 4; ++m)
    #pragma unroll
    for (int n = 0; n < 4; ++n)
      acc[m][n] = (f32x4){0.f, 0.f, 0.f, 0.f};

  #pragma unroll
  for (int ks = 0; ks < 4; ++ks){
    bf16x8 av[4], bv[4];
    #pragma unroll
    for (int m = 0; m < 4; ++m){
      int row = wr * 64 + m * 16 + l15;
      int sp = (ks * 4 + g) ^ (row & 15);
      av[m] = *(const bf16x8*)((const char*)&lds[0][0] + row * 256 + sp * 16);
    }
    #pragma unroll
    for (int n = 0; n < 4; ++n){
      int rowb = wc * 64 + n * 16 + l15;
      int spb = (ks * 4 + g) ^ (rowb & 15);
      bv[n] = *(const bf16x8*)((const char*)&lds[1][0] + rowb * 256 + spb * 16);
    }
    #pragma unroll
    for (int m = 0; m < 4; ++m)
      #pragma unroll
      for (int n = 0; n < 4; ++n)
        acc[m][n] = __builtin_amdgcn_mfma_f32_16x16x32_bf16(av[m], bv[n], acc[m][n], 0, 0, 0);
  }

  float part = 0.f;
  #pragma unroll
  for (int m = 0; m < 4; ++m)
    #pragma unroll
    for (int n = 0; n < 4; ++n)
      #pragma unroll
      for (int r = 0; r < 4; ++r){
        int row = bi * 128 + wr * 64 + m * 16 + g * 4 + r;
        int col = bj * 128 + wc * 64 + n * 16 + l15;
        part += tran[(size_t)row * NN + col] * acc[m][n][r];
      }
  #pragma unroll
  for (int off = 32; off; off >>= 1) part += __shfl_down(part, off);
  if (lane == 0) atomicAdd(&accs[1], part);
}

// ---------------- final combine ----------------
__global__ void k_final(const float* __restrict__ f1, const float* __restrict__ f2,
                        const float* __restrict__ rowsum, const float* __restrict__ colsum,
                        const float* __restrict__ ss, const float* __restrict__ st,
                        const float* __restrict__ accs, float* out){
  __shared__ float red[256];
  int t = threadIdx.x;
  float part = 0.f;
  for (int i = t; i < NN; i += 256){
    part += (f1[i] + 0.5f * ss[i]) * rowsum[i];
    part += (f2[i] + 0.5f * st[i]) * colsum[i];
  }
  red[t] = part; __syncthreads();
  for (int s = 128; s; s >>= 1){ if (t < s) red[t] += red[t + s]; __syncthreads(); }
  if (t == 0){
    float total = red[0] - 2.0f * accs[0] - accs[1];
    out[0] = total;   // reference output is float32
  }
}

extern "C" void kernel_launch(void* const* d_in, const int* in_sizes, int n_in,
                              void* d_out, int out_size, void* d_ws, size_t ws_size,
                              hipStream_t stream)
{
  const float* graph  = (const float*)d_in[0];
  const float* emb    = (const float*)d_in[1];
  const float* prob   = (const float*)d_in[2];
  const float* graphb = (const float*)d_in[3];
  const float* embb   = (const float*)d_in[4];
  const float* probb  = (const float*)d_in[5];
  const float* tran   = (const float*)d_in[6];
  (void)in_sizes; (void)n_in; (void)out_size; (void)ws_size;

  char* ws = (char*)d_ws;
  u16* Cs   = (u16*)(ws + 0);          // 8MB  Cs bf16
  u16* Tm   = (u16*)(ws + 8388608);    // 8MB  T bf16
  u16* Tt   = (u16*)(ws + 16777216);   // 8MB  T^T bf16
  u16* CtT  = (u16*)(ws + 25165824);   // 8MB  Ct^T bf16
  u16* es   = (u16*)(ws + 33554432);   // 512KB
  u16* et   = (u16*)(ws + 34078720);   // 512KB
  float* f1   = (float*)(ws + 34603008);
  float* f2   = (float*)(ws + 34611200);
  float* rs   = (float*)(ws + 34619392);
  float* cls  = (float*)(ws + 34627584);
  float* ss   = (float*)(ws + 34635776);
  float* st   = (float*)(ws + 34643968);
  float* accs = (float*)(ws + 34652160);

  // zero all small scratch (f1..accs) — rs/cls/f2 are atomic-accumulated
  hipMemsetAsync(ws + 34603008, 0, 49216, stream);

  k_prep<<<3072, 256, 0, stream>>>(graph, prob, tran, graphb, probb, emb, embb,
                                   Cs, Tm, Tt, CtT, es, et,
                                   f1, f2, rs, cls, ss, st);
  k_gw<<<256, 512, 0, stream>>>(Cs, Tt, Tm, CtT, accs);
  k_embdot<<<256, 256, 0, stream>>>(es, et, tran, accs);
  k_final<<<1, 256, 0, stream>>>(f1, f2, rs, cls, ss, st, accs, (float*)d_out);
}

// Round 10
// 94.911 us; speedup vs baseline: 1.4466x; 1.1271x over previous
//
#include <hip/hip_runtime.h>
#include <hip/hip_bf16.h>

#define NN 2048
#define DD 128

typedef unsigned short u16;
typedef unsigned int u32;
typedef __attribute__((ext_vector_type(8))) short bf16x8;
typedef __attribute__((ext_vector_type(4))) float f32x4;

__device__ __forceinline__ u16 f2bf(float f){
  u32 u = __float_as_uint(f);
  u32 r = (u + 0x7fffu + ((u >> 16) & 1u)) >> 16;
  return (u16)r;
}

__device__ __forceinline__ void gload16(const void* g, void* l){
  __builtin_amdgcn_global_load_lds(
      (const __attribute__((address_space(1))) u32*)g,
      (__attribute__((address_space(3))) u32*)l, 16, 0, 0);
}

// ================= fused prep: role-dispatched by block range =================

// graph pass: bf16 cast -> Cs, f1[row] = sum(v^2 * prob[c])  (direct write)
__device__ __forceinline__ void rowpass_graph_body(
    int bid, int tid, const float* __restrict__ src, const float* __restrict__ w,
    u16* __restrict__ dst, float* __restrict__ red){
  int wid = tid >> 6, lane = tid & 63;
  int row = bid * 4 + wid;
  const float4* s4 = (const float4*)(src + (size_t)row * NN);
  float acc = 0.f;
  #pragma unroll
  for (int it = 0; it < NN / 256; ++it){
    int c4 = it * 64 + lane;
    float4 v = s4[c4];
    float4 ww = ((const float4*)w)[c4];
    acc += v.x*v.x*ww.x + v.y*v.y*ww.y + v.z*v.z*ww.z + v.w*v.w*ww.w;
    ushort4 o; o.x = f2bf(v.x); o.y = f2bf(v.y); o.z = f2bf(v.z); o.w = f2bf(v.w);
    ((ushort4*)(dst + (size_t)row * NN))[c4] = o;
  }
  #pragma unroll
  for (int off = 32; off; off >>= 1) acc += __shfl_down(acc, off);
  if (lane == 0) red[row] = acc;
}

// tran pass (64x64 tile): write Tm (bf16 copy), Tt (bf16 transpose),
// partial row sums -> atomicAdd(rs), partial col sums -> atomicAdd(cls)
__device__ __forceinline__ void tran_pass_body(
    int bx, int by, int t, float (*tile)[65],
    const float* __restrict__ src,
    u16* __restrict__ Tm, u16* __restrict__ Tt,
    float* __restrict__ rs, float* __restrict__ cls)
{
  int r0 = bx * 64, c0 = by * 64;
  #pragma unroll
  for (int it = 0; it < 4; ++it){
    int chunk = it * 256 + t; int r = chunk >> 4, c4 = chunk & 15;
    float4 v = ((const float4*)(src + (size_t)(r0 + r) * NN + c0))[c4];
    tile[r][c4*4+0] = v.x; tile[r][c4*4+1] = v.y;
    tile[r][c4*4+2] = v.z; tile[r][c4*4+3] = v.w;
    ushort4 o; o.x = f2bf(v.x); o.y = f2bf(v.y); o.z = f2bf(v.z); o.w = f2bf(v.w);
    ((ushort4*)(Tm + (size_t)(r0 + r) * NN + c0))[c4] = o;
  }
  __syncthreads();
  #pragma unroll
  for (int it = 0; it < 4; ++it){
    int chunk = it * 256 + t; int j = chunk >> 4, i4 = chunk & 15;
    ushort4 o;
    o.x = f2bf(tile[i4*4+0][j]); o.y = f2bf(tile[i4*4+1][j]);
    o.z = f2bf(tile[i4*4+2][j]); o.w = f2bf(tile[i4*4+3][j]);
    ((ushort4*)(Tt + (size_t)(c0 + j) * NN + r0))[i4] = o;
  }
  if (t < 64){
    float s = 0.f;
    #pragma unroll
    for (int c = 0; c < 64; ++c) s += tile[t][c];
    atomicAdd(&rs[r0 + t], s);
  } else if (t < 128){
    int c = t - 64; float s = 0.f;
    #pragma unroll
    for (int r = 0; r < 64; ++r) s += tile[r][c];
    atomicAdd(&cls[c0 + c], s);
  }
}

// graphb pass (64x64 tile): write CtT (bf16 transpose),
// f2 partials: f2[j] += sum_i probb[i]*graphb[j,i]^2
__device__ __forceinline__ void graphb_pass_body(
    int bx, int by, int t, float (*tile)[65], float* pb,
    const float* __restrict__ src, const float* __restrict__ probb,
    u16* __restrict__ CtT, float* __restrict__ f2)
{
  int r0 = bx * 64, c0 = by * 64;
  if (t < 64) pb[t] = probb[c0 + t];
  #pragma unroll
  for (int it = 0; it < 4; ++it){
    int chunk = it * 256 + t; int r = chunk >> 4, c4 = chunk & 15;
    float4 v = ((const float4*)(src + (size_t)(r0 + r) * NN + c0))[c4];
    tile[r][c4*4+0] = v.x; tile[r][c4*4+1] = v.y;
    tile[r][c4*4+2] = v.z; tile[r][c4*4+3] = v.w;
  }
  __syncthreads();
  #pragma unroll
  for (int it = 0; it < 4; ++it){
    int chunk = it * 256 + t; int j = chunk >> 4, i4 = chunk & 15;
    ushort4 o;
    o.x = f2bf(tile[i4*4+0][j]); o.y = f2bf(tile[i4*4+1][j]);
    o.z = f2bf(tile[i4*4+2][j]); o.w = f2bf(tile[i4*4+3][j]);
    ((ushort4*)(CtT + (size_t)(c0 + j) * NN + r0))[i4] = o;
  }
  if (t < 64){
    float s = 0.f;
    #pragma unroll
    for (int c = 0; c < 64; ++c){ float v = tile[t][c]; s += v * v * pb[c]; }
    atomicAdd(&f2[r0 + t], s);
  }
}

__device__ __forceinline__ void emb_body(
    int bid, int t, const float* __restrict__ src, u16* __restrict__ dst,
    float* __restrict__ nrm){
  int rloc = t >> 5, lane32 = t & 31;
  int row = bid * 8 + rloc;
  float4 v = ((const float4*)(src + (size_t)row * DD))[lane32];
  float a = v.x*v.x + v.y*v.y + v.z*v.z + v.w*v.w;
  ushort4 o; o.x = f2bf(v.x); o.y = f2bf(v.y); o.z = f2bf(v.z); o.w = f2bf(v.w);
  ((ushort4*)(dst + (size_t)row * DD))[lane32] = o;
  #pragma unroll
  for (int off = 16; off; off >>= 1) a += __shfl_down(a, off, 32);
  if (lane32 == 0) nrm[row] = a;
}

// roles: [0,512) graph | [512,1536) tran | [1536,2560) graphb |
//        [2560,2816) embA | [2816,3072) embB
__global__ __launch_bounds__(256) void k_prep(
    const float* __restrict__ graph,  const float* __restrict__ prob,
    const float* __restrict__ tran,   const float* __restrict__ graphb,
    const float* __restrict__ probb,  const float* __restrict__ emb,
    const float* __restrict__ embb,
    u16* Cs, u16* Tm, u16* Tt, u16* CtT, u16* es, u16* et,
    float* f1, float* f2, float* rs, float* cls, float* ss, float* st)
{
  __shared__ float tile[64][65];
  __shared__ float pb[64];
  int b = blockIdx.x, t = threadIdx.x;
  if (b < 512){
    rowpass_graph_body(b, t, graph, prob, Cs, f1);
  } else if (b < 1536){
    int b2 = b - 512;  tran_pass_body(b2 & 31, b2 >> 5, t, tile, tran, Tm, Tt, rs, cls);
  } else if (b < 2560){
    int b2 = b - 1536; graphb_pass_body(b2 & 31, b2 >> 5, t, tile, pb, graphb, probb, CtT, f2);
  } else if (b < 2816){
    emb_body(b - 2560, t, emb, es, ss);
  } else {
    emb_body(b - 2816, t, embb, et, st);
  }
}

// ================= main dual-GEMM: sum( (Cs@T) .* (T@Ct) ) =================
// 128x128 dual tile, grid 256 (1 block/CU), BK=64 double-buffered (128KB LDS).
// Tile layout: [128 rows][64 K-cols] bf16 = 128B/row = 8x16B slots,
// phys slot = data_slot ^ (row&7) (pre-swizzled global source, linear LDS dest).
// waves 0-3: U = Cs @ T (A1=Cs, B1^T=Tt); waves 4-7: V = T @ Ct (A2=T, B2^T=CtT)
__global__ __launch_bounds__(512, 2) void k_gw(
    const u16* __restrict__ Cs, const u16* __restrict__ Tt,
    const u16* __restrict__ Tm, const u16* __restrict__ CtT,
    float* __restrict__ accs)
{
  __shared__ u16 lds[2][4][8192];   // 2 buf x {A1,B1,A2,B2} x 16KB = 128KB
  const int tid = threadIdx.x;
  const int bid = blockIdx.x;
  const int swz = (bid & 7) * 32 + (bid >> 3);   // XCD swizzle (256 % 8 == 0)
  const int bi = swz >> 4, bk = swz & 15;

  const u16* srcs[4] = {Cs, Tt, Tm, CtT};
  const int panels[4] = {bi * 128, bk * 128, bi * 128, bk * 128};

  const int w = tid >> 6, lane = tid & 63;
  const int l15 = lane & 15, g = lane >> 4;
  const int gsel = w >> 2, wg = w & 3, wr = wg >> 1, wc = wg & 1;

  // staging: per tile 1024 chunks of 16B; thread t stages chunks {tid, tid+512}.
  // chunk ch: row = ch>>3, s = ch&7, global slot = s^(row&7).
  // chunk tid+512 -> row+64, same slot math.
  const int s_row = tid >> 3;
  const int s_gslot = (tid & 7) ^ (s_row & 7);

  f32x4 acc[4][4];
  #pragma unroll
  for (int m = 0; m < 4; ++m)
    #pragma unroll
    for (int n = 0; n < 4; ++n)
      acc[m][n] = (f32x4){0.f, 0.f, 0.f, 0.f};

  // read offsets (u16 units): row*64 + pslot*8, pslot = (kk*4+g)^(row&7)
  int offA[4][2], offB[4][2];
  #pragma unroll
  for (int m = 0; m < 4; ++m){
    int row = wr * 64 + m * 16 + l15;
    int rowb = wc * 64 + m * 16 + l15;
    #pragma unroll
    for (int kk = 0; kk < 2; ++kk){
      offA[m][kk] = row * 64 + ((((kk << 2) | g)) ^ (row & 7)) * 8;
      offB[m][kk] = rowb * 64 + ((((kk << 2) | g)) ^ (rowb & 7)) * 8;
    }
  }

  auto stage = [&](int buf, int kt){
    const size_t col = (size_t)kt * 64 + s_gslot * 8;
    #pragma unroll
    for (int tt = 0; tt < 4; ++tt){
      gload16(srcs[tt] + (size_t)(panels[tt] + s_row) * NN + col,
              &lds[buf][tt][w * 512]);
      gload16(srcs[tt] + (size_t)(panels[tt] + s_row + 64) * NN + col,
              &lds[buf][tt][4096 + w * 512]);
    }
  };

  stage(0, 0);
  __syncthreads();

  const int NT = NN / 64;
  for (int kt = 0; kt < NT; ++kt){
    int cur = kt & 1;
    if (kt + 1 < NT) stage(cur ^ 1, kt + 1);
    const u16* tA = &lds[cur][gsel * 2][0];
    const u16* tB = &lds[cur][gsel * 2 + 1][0];
    #pragma unroll
    for (int kk = 0; kk < 2; ++kk){
      bf16x8 av[4], bv[4];
      #pragma unroll
      for (int m = 0; m < 4; ++m) av[m] = *(const bf16x8*)(tA + offA[m][kk]);
      #pragma unroll
      for (int n = 0; n < 4; ++n) bv[n] = *(const bf16x8*)(tB + offB[n][kk]);
      #pragma unroll
      for (int m = 0; m < 4; ++m)
        #pragma unroll
        for (int n = 0; n < 4; ++n)
          acc[m][n] = __builtin_amdgcn_mfma_f32_16x16x32_bf16(av[m], bv[n], acc[m][n], 0, 0, 0);
    }
    __syncthreads();
  }

  // epilogue: U-waves stash to LDS (f32 128x128 = 64KB = lds[0]), V-waves dot.
  float* ustash = (float*)&lds[0][0][0];
  if (gsel == 0){
    #pragma unroll
    for (int m = 0; m < 4; ++m)
      #pragma unroll
      for (int n = 0; n < 4; ++n)
        #pragma unroll
        for (int r = 0; r < 4; ++r){
          int row = wr * 64 + m * 16 + g * 4 + r;   // C/D: row=(lane>>4)*4+reg
          int col = wc * 64 + n * 16 + l15;         //      col=lane&15
          ustash[row * 128 + col] = acc[m][n][r];
        }
  }
  __syncthreads();
  if (gsel == 1){
    float part = 0.f;
    #pragma unroll
    for (int m = 0; m < 4; ++m)
      #pragma unroll
      for (int n = 0; n < 4; ++n)
        #pragma unroll
        for (int r = 0; r < 4; ++r){
          int row = wr * 64 + m * 16 + g * 4 + r;
          int col = wc * 64 + n * 16 + l15;
          part += acc[m][n][r] * ustash[row * 128 + col];
        }
    #pragma unroll
    for (int off = 32; off; off >>= 1) part += __shfl_down(part, off);
    if (lane == 0) atomicAdd(&accs[0], part);
  }
}

// ---------------- term4: sum( T .* (es @ et^T) ) ----------------
__global__ __launch_bounds__(256, 2) void k_embdot(
    const u16* __restrict__ es, const u16* __restrict__ et,
    const float* __restrict__ tran, float* __restrict__ accs)
{
  __shared__ u16 lds[2][16384];   // es tile 32KB, et tile 32KB ([128][128] bf16)
  const int tid = threadIdx.x;
  const int bid = blockIdx.x;
  const int swz = (bid & 7) * 32 + (bid >> 3);
  const int bi = swz >> 4, bj = swz & 15;
  const int w = tid >> 6, lane = tid & 63;
  const int l15 = lane & 15, g = lane >> 4;
  const int wr = w >> 1, wc = w & 1;

  const u16* srcs[2] = {es, et};
  const int panels[2] = {bi * 128, bj * 128};

  #pragma unroll
  for (int tt = 0; tt < 2; ++tt){
    #pragma unroll
    for (int it = 0; it < 8; ++it){
      int chunk = w * 8 + it;            // 0..31, 1KB each
      int r = chunk * 4 + g;             // 0..127
      int s = l15 ^ (r & 15);
      gload16(srcs[tt] + (size_t)(panels[tt] + r) * DD + s * 8,
              &lds[tt][chunk * 512]);
    }
  }
  __syncthreads();

  f32x4 acc[4][4];
  #pragma unroll
  for (int m = 0; m < 4; ++m)
    #pragma unroll
    for (int n = 0; n < 4; ++n)
      acc[m][n] = (f32x4){0.f, 0.f, 0.f, 0.f};

  #pragma unroll
  for (int ks = 0; ks < 4; ++ks){
    bf16x8 av[4], bv[4];
    #pragma unroll
    for (int m = 0; m < 4; ++m){
      int row = wr * 64 + m * 16 + l15;
      int sp = (ks * 4 + g) ^ (row & 15);
      av[m] = *(const bf16x8*)((const char*)&lds[0][0] + row * 256 + sp * 16);
    }
    #pragma unroll
    for (int n = 0; n < 4; ++n){
      int rowb = wc * 64 + n * 16 + l15;
      int spb = (ks * 4 + g) ^ (rowb & 15);
      bv[n] = *(const bf16x8*)((const char*)&lds[1][0] + rowb * 256 + spb * 16);
    }
    #pragma unroll
    for (int m = 0; m < 4; ++m)
      #pragma unroll
      for (int n = 0; n < 4; ++n)
        acc[m][n] = __builtin_amdgcn_mfma_f32_16x16x32_bf16(av[m], bv[n], acc[m][n], 0, 0, 0);
  }

  float part = 0.f;
  #pragma unroll
  for (int m = 0; m < 4; ++m)
    #pragma unroll
    for (int n = 0; n < 4; ++n)
      #pragma unroll
      for (int r = 0; r < 4; ++r){
        int row = bi * 128 + wr * 64 + m * 16 + g * 4 + r;
        int col = bj * 128 + wc * 64 + n * 16 + l15;
        part += tran[(size_t)row * NN + col] * acc[m][n][r];
      }
  #pragma unroll
  for (int off = 32; off; off >>= 1) part += __shfl_down(part, off);
  if (lane == 0) atomicAdd(&accs[1], part);
}

// ---------------- final combine ----------------
__global__ void k_final(const float* __restrict__ f1, const float* __restrict__ f2,
                        const float* __restrict__ rowsum, const float* __restrict__ colsum,
                        const float* __restrict__ ss, const float* __restrict__ st,
                        const float* __restrict__ accs, float* out){
  __shared__ float red[256];
  int t = threadIdx.x;
  float part = 0.f;
  for (int i = t; i < NN; i += 256){
    part += (f1[i] + 0.5f * ss[i]) * rowsum[i];
    part += (f2[i] + 0.5f * st[i]) * colsum[i];
  }
  red[t] = part; __syncthreads();
  for (int s = 128; s; s >>= 1){ if (t < s) red[t] += red[t + s]; __syncthreads(); }
  if (t == 0){
    float total = red[0] - 2.0f * accs[0] - accs[1];
    out[0] = total;   // reference output is float32
  }
}

extern "C" void kernel_launch(void* const* d_in, const int* in_sizes, int n_in,
                              void* d_out, int out_size, void* d_ws, size_t ws_size,
                              hipStream_t stream)
{
  const float* graph  = (const float*)d_in[0];
  const float* emb    = (const float*)d_in[1];
  const float* prob   = (const float*)d_in[2];
  const float* graphb = (const float*)d_in[3];
  const float* embb   = (const float*)d_in[4];
  const float* probb  = (const float*)d_in[5];
  const float* tran   = (const float*)d_in[6];
  (void)in_sizes; (void)n_in; (void)out_size; (void)ws_size;

  char* ws = (char*)d_ws;
  u16* Cs   = (u16*)(ws + 0);          // 8MB  Cs bf16
  u16* Tm   = (u16*)(ws + 8388608);    // 8MB  T bf16
  u16* Tt   = (u16*)(ws + 16777216);   // 8MB  T^T bf16
  u16* CtT  = (u16*)(ws + 25165824);   // 8MB  Ct^T bf16
  u16* es   = (u16*)(ws + 33554432);   // 512KB
  u16* et   = (u16*)(ws + 34078720);   // 512KB
  float* f1   = (float*)(ws + 34603008);
  float* f2   = (float*)(ws + 34611200);
  float* rs   = (float*)(ws + 34619392);
  float* cls  = (float*)(ws + 34627584);
  float* ss   = (float*)(ws + 34635776);
  float* st   = (float*)(ws + 34643968);
  float* accs = (float*)(ws + 34652160);

  // zero all small scratch (f1..accs) — rs/cls/f2 are atomic-accumulated
  hipMemsetAsync(ws + 34603008, 0, 49216, stream);

  k_prep<<<3072, 256, 0, stream>>>(graph, prob, tran, graphb, probb, emb, embb,
                                   Cs, Tm, Tt, CtT, es, et,
                                   f1, f2, rs, cls, ss, st);
  k_gw<<<256, 512, 0, stream>>>(Cs, Tt, Tm, CtT, accs);
  k_embdot<<<256, 256, 0, stream>>>(es, et, tran, accs);
  k_final<<<1, 256, 0, stream>>>(f1, f2, rs, cls, ss, st, accs, (float*)d_out);
}

// Round 11
// 92.612 us; speedup vs baseline: 1.4825x; 1.0248x over previous
//
#include <hip/hip_runtime.h>
#include <hip/hip_bf16.h>

#define NN 2048
#define DD 128

typedef unsigned short u16;
typedef unsigned int u32;
typedef __attribute__((ext_vector_type(8))) short bf16x8;
typedef __attribute__((ext_vector_type(4))) float f32x4;

__device__ __forceinline__ u16 f2bf(float f){
  u32 u = __float_as_uint(f);
  u32 r = (u + 0x7fffu + ((u >> 16) & 1u)) >> 16;
  return (u16)r;
}

__device__ __forceinline__ void gload16(const void* g, void* l){
  __builtin_amdgcn_global_load_lds(
      (const __attribute__((address_space(1))) u32*)g,
      (__attribute__((address_space(3))) u32*)l, 16, 0, 0);
}

// ================= fused prep: role-dispatched by block range =================

// graph pass: bf16 cast -> Cs, f1[row] = sum(v^2 * prob[c])  (direct write)
__device__ __forceinline__ void rowpass_graph_body(
    int bid, int tid, const float* __restrict__ src, const float* __restrict__ w,
    u16* __restrict__ dst, float* __restrict__ red){
  int wid = tid >> 6, lane = tid & 63;
  int row = bid * 4 + wid;
  const float4* s4 = (const float4*)(src + (size_t)row * NN);
  float acc = 0.f;
  #pragma unroll
  for (int it = 0; it < NN / 256; ++it){
    int c4 = it * 64 + lane;
    float4 v = s4[c4];
    float4 ww = ((const float4*)w)[c4];
    acc += v.x*v.x*ww.x + v.y*v.y*ww.y + v.z*v.z*ww.z + v.w*v.w*ww.w;
    ushort4 o; o.x = f2bf(v.x); o.y = f2bf(v.y); o.z = f2bf(v.z); o.w = f2bf(v.w);
    ((ushort4*)(dst + (size_t)row * NN))[c4] = o;
  }
  #pragma unroll
  for (int off = 32; off; off >>= 1) acc += __shfl_down(acc, off);
  if (lane == 0) red[row] = acc;
}

// tran pass (64x64 tile): write Tm (bf16 copy), Tt (bf16 transpose),
// partial row sums -> atomicAdd(rs), partial col sums -> atomicAdd(cls)
__device__ __forceinline__ void tran_pass_body(
    int bx, int by, int t, float (*tile)[65],
    const float* __restrict__ src,
    u16* __restrict__ Tm, u16* __restrict__ Tt,
    float* __restrict__ rs, float* __restrict__ cls)
{
  int r0 = bx * 64, c0 = by * 64;
  #pragma unroll
  for (int it = 0; it < 4; ++it){
    int chunk = it * 256 + t; int r = chunk >> 4, c4 = chunk & 15;
    float4 v = ((const float4*)(src + (size_t)(r0 + r) * NN + c0))[c4];
    tile[r][c4*4+0] = v.x; tile[r][c4*4+1] = v.y;
    tile[r][c4*4+2] = v.z; tile[r][c4*4+3] = v.w;
    ushort4 o; o.x = f2bf(v.x); o.y = f2bf(v.y); o.z = f2bf(v.z); o.w = f2bf(v.w);
    ((ushort4*)(Tm + (size_t)(r0 + r) * NN + c0))[c4] = o;
  }
  __syncthreads();
  #pragma unroll
  for (int it = 0; it < 4; ++it){
    int chunk = it * 256 + t; int j = chunk >> 4, i4 = chunk & 15;
    ushort4 o;
    o.x = f2bf(tile[i4*4+0][j]); o.y = f2bf(tile[i4*4+1][j]);
    o.z = f2bf(tile[i4*4+2][j]); o.w = f2bf(tile[i4*4+3][j]);
    ((ushort4*)(Tt + (size_t)(c0 + j) * NN + r0))[i4] = o;
  }
  if (t < 64){
    float s = 0.f;
    #pragma unroll
    for (int c = 0; c < 64; ++c) s += tile[t][c];
    atomicAdd(&rs[r0 + t], s);
  } else if (t < 128){
    int c = t - 64; float s = 0.f;
    #pragma unroll
    for (int r = 0; r < 64; ++r) s += tile[r][c];
    atomicAdd(&cls[c0 + c], s);
  }
}

// graphb pass (64x64 tile): write CtT (bf16 transpose),
// f2 partials: f2[j] += sum_i probb[i]*graphb[j,i]^2
__device__ __forceinline__ void graphb_pass_body(
    int bx, int by, int t, float (*tile)[65], float* pb,
    const float* __restrict__ src, const float* __restrict__ probb,
    u16* __restrict__ CtT, float* __restrict__ f2)
{
  int r0 = bx * 64, c0 = by * 64;
  if (t < 64) pb[t] = probb[c0 + t];
  #pragma unroll
  for (int it = 0; it < 4; ++it){
    int chunk = it * 256 + t; int r = chunk >> 4, c4 = chunk & 15;
    float4 v = ((const float4*)(src + (size_t)(r0 + r) * NN + c0))[c4];
    tile[r][c4*4+0] = v.x; tile[r][c4*4+1] = v.y;
    tile[r][c4*4+2] = v.z; tile[r][c4*4+3] = v.w;
  }
  __syncthreads();
  #pragma unroll
  for (int it = 0; it < 4; ++it){
    int chunk = it * 256 + t; int j = chunk >> 4, i4 = chunk & 15;
    ushort4 o;
    o.x = f2bf(tile[i4*4+0][j]); o.y = f2bf(tile[i4*4+1][j]);
    o.z = f2bf(tile[i4*4+2][j]); o.w = f2bf(tile[i4*4+3][j]);
    ((ushort4*)(CtT + (size_t)(c0 + j) * NN + r0))[i4] = o;
  }
  if (t < 64){
    float s = 0.f;
    #pragma unroll
    for (int c = 0; c < 64; ++c){ float v = tile[t][c]; s += v * v * pb[c]; }
    atomicAdd(&f2[r0 + t], s);
  }
}

__device__ __forceinline__ void emb_body(
    int bid, int t, const float* __restrict__ src, u16* __restrict__ dst,
    float* __restrict__ nrm){
  int rloc = t >> 5, lane32 = t & 31;
  int row = bid * 8 + rloc;
  float4 v = ((const float4*)(src + (size_t)row * DD))[lane32];
  float a = v.x*v.x + v.y*v.y + v.z*v.z + v.w*v.w;
  ushort4 o; o.x = f2bf(v.x); o.y = f2bf(v.y); o.z = f2bf(v.z); o.w = f2bf(v.w);
  ((ushort4*)(dst + (size_t)row * DD))[lane32] = o;
  #pragma unroll
  for (int off = 16; off; off >>= 1) a += __shfl_down(a, off, 32);
  if (lane32 == 0) nrm[row] = a;
}

// roles: [0,512) graph | [512,1536) tran | [1536,2560) graphb |
//        [2560,2816) embA | [2816,3072) embB
__global__ __launch_bounds__(256) void k_prep(
    const float* __restrict__ graph,  const float* __restrict__ prob,
    const float* __restrict__ tran,   const float* __restrict__ graphb,
    const float* __restrict__ probb,  const float* __restrict__ emb,
    const float* __restrict__ embb,
    u16* Cs, u16* Tm, u16* Tt, u16* CtT, u16* es, u16* et,
    float* f1, float* f2, float* rs, float* cls, float* ss, float* st)
{
  __shared__ float tile[64][65];
  __shared__ float pb[64];
  int b = blockIdx.x, t = threadIdx.x;
  if (b < 512){
    rowpass_graph_body(b, t, graph, prob, Cs, f1);
  } else if (b < 1536){
    int b2 = b - 512;  tran_pass_body(b2 & 31, b2 >> 5, t, tile, tran, Tm, Tt, rs, cls);
  } else if (b < 2560){
    int b2 = b - 1536; graphb_pass_body(b2 & 31, b2 >> 5, t, tile, pb, graphb, probb, CtT, f2);
  } else if (b < 2816){
    emb_body(b - 2560, t, emb, es, ss);
  } else {
    emb_body(b - 2816, t, embb, et, st);
  }
}

// ================= main dual-GEMM: sum( (Cs@T) .* (T@Ct) ) =================
// 128x128 dual tile, grid 256 (1 block/CU), BK=64 double-buffered (128KB LDS).
// K-loop uses counted vmcnt(8) + raw s_barrier: prefetch loads stay in flight
// across barriers (no vmcnt(0) drain in the main loop).
__global__ __launch_bounds__(512, 2) void k_gw(
    const u16* __restrict__ Cs, const u16* __restrict__ Tt,
    const u16* __restrict__ Tm, const u16* __restrict__ CtT,
    float* __restrict__ accs)
{
  __shared__ u16 lds[2][4][8192];   // 2 buf x {A1,B1,A2,B2} x 16KB = 128KB
  const int tid = threadIdx.x;
  const int bid = blockIdx.x;
  const int swz = (bid & 7) * 32 + (bid >> 3);   // XCD swizzle (256 % 8 == 0)
  const int bi = swz >> 4, bk = swz & 15;

  const u16* srcs[4] = {Cs, Tt, Tm, CtT};
  const int panels[4] = {bi * 128, bk * 128, bi * 128, bk * 128};

  const int w = tid >> 6, lane = tid & 63;
  const int l15 = lane & 15, g = lane >> 4;
  const int gsel = w >> 2, wg = w & 3, wr = wg >> 1, wc = wg & 1;

  // staging: per tile 1024 chunks of 16B; thread t stages chunks {tid, tid+512}.
  const int s_row = tid >> 3;
  const int s_gslot = (tid & 7) ^ (s_row & 7);

  f32x4 acc[4][4];
  #pragma unroll
  for (int m = 0; m < 4; ++m)
    #pragma unroll
    for (int n = 0; n < 4; ++n)
      acc[m][n] = (f32x4){0.f, 0.f, 0.f, 0.f};

  // read offsets (u16 units): row*64 + pslot*8, pslot = (kk*4+g)^(row&7)
  int offA[4][2], offB[4][2];
  #pragma unroll
  for (int m = 0; m < 4; ++m){
    int row = wr * 64 + m * 16 + l15;
    int rowb = wc * 64 + m * 16 + l15;
    #pragma unroll
    for (int kk = 0; kk < 2; ++kk){
      offA[m][kk] = row * 64 + ((((kk << 2) | g)) ^ (row & 7)) * 8;
      offB[m][kk] = rowb * 64 + ((((kk << 2) | g)) ^ (rowb & 7)) * 8;
    }
  }

  auto stage = [&](int buf, int kt){
    const size_t col = (size_t)kt * 64 + s_gslot * 8;
    #pragma unroll
    for (int tt = 0; tt < 4; ++tt){
      gload16(srcs[tt] + (size_t)(panels[tt] + s_row) * NN + col,
              &lds[buf][tt][w * 512]);
      gload16(srcs[tt] + (size_t)(panels[tt] + s_row + 64) * NN + col,
              &lds[buf][tt][4096 + w * 512]);
    }
  };

  const int NT = NN / 64;
  stage(0, 0);                       // 8 loads in flight
  stage(1, 1);                       // 16 in flight
  for (int kt = 0; kt < NT; ++kt){
    int cur = kt & 1;
    // wait only for the OLDEST stage (the one that filled buf cur); the newer
    // 8 loads stay in flight across the barrier.
    asm volatile("s_waitcnt vmcnt(8)" ::: "memory");
    __builtin_amdgcn_s_barrier();    // buf cur ready for all waves

    const u16* tA = &lds[cur][gsel * 2][0];
    const u16* tB = &lds[cur][gsel * 2 + 1][0];
    bf16x8 av[4][2], bv[4][2];
    #pragma unroll
    for (int kk = 0; kk < 2; ++kk){
      #pragma unroll
      for (int m = 0; m < 4; ++m) av[m][kk] = *(const bf16x8*)(tA + offA[m][kk]);
      #pragma unroll
      for (int n = 0; n < 4; ++n) bv[n][kk] = *(const bf16x8*)(tB + offB[n][kk]);
    }
    asm volatile("s_waitcnt lgkmcnt(0)" ::: "memory");
    __builtin_amdgcn_sched_barrier(0);
    __builtin_amdgcn_s_barrier();    // all waves done reading buf cur

    // overwrite buf cur with tile kt+2 (clamped: uniform 8 loads/iter so the
    // vmcnt(8) literal stays correct; clamped stages are never read)
    int kn = (kt + 2 < NT) ? (kt + 2) : (NT - 1);
    stage(cur, kn);

    #pragma unroll
    for (int kk = 0; kk < 2; ++kk)
      #pragma unroll
      for (int m = 0; m < 4; ++m)
        #pragma unroll
        for (int n = 0; n < 4; ++n)
          acc[m][n] = __builtin_amdgcn_mfma_f32_16x16x32_bf16(av[m][kk], bv[n][kk], acc[m][n], 0, 0, 0);
  }

  __syncthreads();   // full drain (vmcnt 0) before LDS reuse as ustash

  // epilogue: U-waves stash to LDS (f32 128x128 = 64KB = lds[0]), V-waves dot.
  float* ustash = (float*)&lds[0][0][0];
  if (gsel == 0){
    #pragma unroll
    for (int m = 0; m < 4; ++m)
      #pragma unroll
      for (int n = 0; n < 4; ++n)
        #pragma unroll
        for (int r = 0; r < 4; ++r){
          int row = wr * 64 + m * 16 + g * 4 + r;   // C/D: row=(lane>>4)*4+reg
          int col = wc * 64 + n * 16 + l15;         //      col=lane&15
          ustash[row * 128 + col] = acc[m][n][r];
        }
  }
  __syncthreads();
  if (gsel == 1){
    float part = 0.f;
    #pragma unroll
    for (int m = 0; m < 4; ++m)
      #pragma unroll
      for (int n = 0; n < 4; ++n)
        #pragma unroll
        for (int r = 0; r < 4; ++r){
          int row = wr * 64 + m * 16 + g * 4 + r;
          int col = wc * 64 + n * 16 + l15;
          part += acc[m][n][r] * ustash[row * 128 + col];
        }
    #pragma unroll
    for (int off = 32; off; off >>= 1) part += __shfl_down(part, off);
    if (lane == 0) atomicAdd(&accs[0], part);
  }
}

// ---------------- term4: sum( T .* (es @ et^T) ) ----------------
__global__ __launch_bounds__(256, 2) void k_embdot(
    const u16* __restrict__ es, const u16* __restrict__ et,
    const float* __restrict__ tran, float* __restrict__ accs)
{
  __shared__ u16 lds[2][16384];   // es tile 32KB, et tile 32KB ([128][128] bf16)
  const int tid = threadIdx.x;
  const int bid = blockIdx.x;
  const int swz = (bid & 7) * 32 + (bid >> 3);
  const int bi = swz >> 4, bj = swz & 15;
  const int w = tid >> 6, lane = tid & 63;
  const int l15 = lane & 15, g = lane >> 4;
  const int wr = w >> 1, wc = w & 1;

  const u16* srcs[2] = {es, et};
  const int panels[2] = {bi * 128, bj * 128};

  #pragma unroll
  for (int tt = 0; tt < 2; ++tt){
    #pragma unroll
    for (int it = 0; it < 8; ++it){
      int chunk = w * 8 + it;            // 0..31, 1KB each
      int r = chunk * 4 + g;             // 0..127
      int s = l15 ^ (r & 15);
      gload16(srcs[tt] + (size_t)(panels[tt] + r) * DD + s * 8,
              &lds[tt][chunk * 512]);
    }
  }
  __syncthreads();

  f32x4 acc[4][4];
  #pragma unroll
  for (int m = 0; m < 4; ++m)
    #pragma unroll
    for (int n = 0; n < 4; ++n)
      acc[m][n] = (f32x4){0.f, 0.f, 0.f, 0.f};

  #pragma unroll
  for (int ks = 0; ks < 4; ++ks){
    bf16x8 av[4], bv[4];
    #pragma unroll
    for (int m = 0; m < 4; ++m){
      int row = wr * 64 + m * 16 + l15;
      int sp = (ks * 4 + g) ^ (row & 15);
      av[m] = *(const bf16x8*)((const char*)&lds[0][0] + row * 256 + sp * 16);
    }
    #pragma unroll
    for (int n = 0; n < 4; ++n){
      int rowb = wc * 64 + n * 16 + l15;
      int spb = (ks * 4 + g) ^ (rowb & 15);
      bv[n] = *(const bf16x8*)((const char*)&lds[1][0] + rowb * 256 + spb * 16);
    }
    #pragma unroll
    for (int m = 0; m < 4; ++m)
      #pragma unroll
      for (int n = 0; n < 4; ++n)
        acc[m][n] = __builtin_amdgcn_mfma_f32_16x16x32_bf16(av[m], bv[n], acc[m][n], 0, 0, 0);
  }

  float part = 0.f;
  #pragma unroll
  for (int m = 0; m < 4; ++m)
    #pragma unroll
    for (int n = 0; n < 4; ++n)
      #pragma unroll
      for (int r = 0; r < 4; ++r){
        int row = bi * 128 + wr * 64 + m * 16 + g * 4 + r;
        int col = bj * 128 + wc * 64 + n * 16 + l15;
        part += tran[(size_t)row * NN + col] * acc[m][n][r];
      }
  #pragma unroll
  for (int off = 32; off; off >>= 1) part += __shfl_down(part, off);
  if (lane == 0) atomicAdd(&accs[1], part);
}

// ---------------- final combine ----------------
__global__ void k_final(const float* __restrict__ f1, const float* __restrict__ f2,
                        const float* __restrict__ rowsum, const float* __restrict__ colsum,
                        const float* __restrict__ ss, const float* __restrict__ st,
                        const float* __restrict__ accs, float* out){
  __shared__ float red[256];
  int t = threadIdx.x;
  float part = 0.f;
  for (int i = t; i < NN; i += 256){
    part += (f1[i] + 0.5f * ss[i]) * rowsum[i];
    part += (f2[i] + 0.5f * st[i]) * colsum[i];
  }
  red[t] = part; __syncthreads();
  for (int s = 128; s; s >>= 1){ if (t < s) red[t] += red[t + s]; __syncthreads(); }
  if (t == 0){
    float total = red[0] - 2.0f * accs[0] - accs[1];
    out[0] = total;   // reference output is float32
  }
}

extern "C" void kernel_launch(void* const* d_in, const int* in_sizes, int n_in,
                              void* d_out, int out_size, void* d_ws, size_t ws_size,
                              hipStream_t stream)
{
  const float* graph  = (const float*)d_in[0];
  const float* emb    = (const float*)d_in[1];
  const float* prob   = (const float*)d_in[2];
  const float* graphb = (const float*)d_in[3];
  const float* embb   = (const float*)d_in[4];
  const float* probb  = (const float*)d_in[5];
  const float* tran   = (const float*)d_in[6];
  (void)in_sizes; (void)n_in; (void)out_size; (void)ws_size;

  char* ws = (char*)d_ws;
  u16* Cs   = (u16*)(ws + 0);          // 8MB  Cs bf16
  u16* Tm   = (u16*)(ws + 8388608);    // 8MB  T bf16
  u16* Tt   = (u16*)(ws + 16777216);   // 8MB  T^T bf16
  u16* CtT  = (u16*)(ws + 25165824);   // 8MB  Ct^T bf16
  u16* es   = (u16*)(ws + 33554432);   // 512KB
  u16* et   = (u16*)(ws + 34078720);   // 512KB
  float* f1   = (float*)(ws + 34603008);
  float* f2   = (float*)(ws + 34611200);
  float* rs   = (float*)(ws + 34619392);
  float* cls  = (float*)(ws + 34627584);
  float* ss   = (float*)(ws + 34635776);
  float* st   = (float*)(ws + 34643968);
  float* accs = (float*)(ws + 34652160);

  // zero all small scratch (f1..accs) — rs/cls/f2 are atomic-accumulated
  hipMemsetAsync(ws + 34603008, 0, 49216, stream);

  k_prep<<<3072, 256, 0, stream>>>(graph, prob, tran, graphb, probb, emb, embb,
                                   Cs, Tm, Tt, CtT, es, et,
                                   f1, f2, rs, cls, ss, st);
  k_gw<<<256, 512, 0, stream>>>(Cs, Tt, Tm, CtT, accs);
  k_embdot<<<256, 256, 0, stream>>>(es, et, tran, accs);
  k_final<<<1, 256, 0, stream>>>(f1, f2, rs, cls, ss, st, accs, (float*)d_out);
}